// Round 1
// baseline (1646.862 us; speedup 1.0000x reference)
//
#include <hip/hip_runtime.h>

// ---------------------------------------------------------------------------
// TransformerBlock: B=2 T=2048 C=2048 H=16 HD=128 MLP=8192, causal, relu^2 MLP
// Round 1: correctness-first MFMA pipeline.
//
// Layout assumptions (verified per cdna_hip_programming.md §3, learn_hip m89/m91):
//   mfma_f32_16x16x32_bf16:  A[m=lane&15][k=(lane>>4)*8+j]
//                            B[n=lane&15][k=(lane>>4)*8+j]   (NT form)
//                            D[row=(lane>>4)*4+reg][col=lane&15]
//
// Runtime dtype detection: harness may store the fp32 reference tensors as
// bf16. detect_dtype_kernel inspects even ushort slots of x: for an fp32
// buffer these are low-mantissa garbage (uniform exponent); for bf16 they are
// N(0,1) values. Flag (1=fp32, 0=bf16) lives at d_ws offset 0.
// ---------------------------------------------------------------------------

typedef __bf16 bf16x8 __attribute__((ext_vector_type(8)));
typedef __bf16 bf16x4 __attribute__((ext_vector_type(4)));
typedef float  f32x4  __attribute__((ext_vector_type(4)));

static __device__ __forceinline__ __bf16 tobf(float f) { return (__bf16)f; }

// ---------------------------------------------------------------------------
__global__ void detect_dtype_kernel(const unsigned short* __restrict__ xh,
                                    int* __restrict__ flag) {
    int t = threadIdx.x;                       // one wave of 64
    unsigned short u = xh[2 * t];              // even ushort slots
    int e = (u >> 7) & 0xFF;                   // bf16 exponent field
    bool outlier = (e < 100) || (e > 131);     // implausible for N(0,1)
    unsigned long long m = __ballot(outlier);
    if (t == 0) *flag = (__popcll(m) >= 16) ? 1 : 0;   // 1 => fp32 buffers
}

// ---------------------------------------------------------------------------
// rmsnorm: row of C=2048, one block per row, 256 threads x 8 elements.
// SRC=0: input dtype per runtime flag. SRC=1: input is fp32 (our own x1).
template <int SRC>
__global__ __launch_bounds__(256) void rmsnorm_kernel(
    const void* __restrict__ xp, __bf16* __restrict__ h,
    const int* __restrict__ flagp) {
    constexpr int C = 2048;
    const int row = blockIdx.x, t = threadIdx.x;
    float vals[8];
    bool f32in = (SRC == 1) || (*flagp != 0);
    if (f32in) {
        const float4* xr = (const float4*)((const float*)xp + (size_t)row * C);
        float4 a = xr[2 * t], b = xr[2 * t + 1];
        vals[0] = a.x; vals[1] = a.y; vals[2] = a.z; vals[3] = a.w;
        vals[4] = b.x; vals[5] = b.y; vals[6] = b.z; vals[7] = b.w;
    } else {
        bf16x8 a = *((const bf16x8*)((const __bf16*)xp + (size_t)row * C) + t);
#pragma unroll
        for (int j = 0; j < 8; ++j) vals[j] = (float)a[j];
    }
    float ss = 0.f;
#pragma unroll
    for (int j = 0; j < 8; ++j) ss += vals[j] * vals[j];
#pragma unroll
    for (int off = 32; off > 0; off >>= 1) ss += __shfl_down(ss, off);
    __shared__ float red[4];
    if ((t & 63) == 0) red[t >> 6] = ss;
    __syncthreads();
    float mean = (red[0] + red[1] + red[2] + red[3]) * (1.0f / C);
    float sc = rsqrtf(mean + 1e-5f);
    bf16x8 o;
#pragma unroll
    for (int j = 0; j < 8; ++j) o[j] = tobf(vals[j] * sc);
    *((bf16x8*)(h + (size_t)row * C) + t) = o;
}

// ---------------------------------------------------------------------------
// NT GEMM: out[M,N] = A[M,K](bf16) @ W[N,K]^T (+epilogue)
// EPI 0: store bf16
// EPI 1: out fp32 = res(dtype per flag) + acc        (wo projection -> x1)
// EPI 2: store bf16 relu(acc)^2                      (fc1)
// EPI 3: out(dtype per flag) = res(fp32) + acc       (fc2 -> d_out)
// W dtype per runtime flag (fp32 converted during staging, or bf16 direct).
template <int EPI>
__global__ __launch_bounds__(256) void gemm_nt(
    const __bf16* __restrict__ A, const void* __restrict__ Wp,
    void* __restrict__ outp, const void* __restrict__ resp,
    int M, int N, int K, const int* __restrict__ flagp) {
    __shared__ __bf16 As[128][40];   // 128x32 tile, pitch 40 (bank spread)
    __shared__ __bf16 Bs[128][40];
    const bool wf32 = (*flagp != 0);
    const int t = threadIdx.x;
    const int wave = t >> 6, lane = t & 63;
    const int lr = lane & 15, lq = lane >> 4;
    const int wm = wave & 1, wn = wave >> 1;
    const int m0 = blockIdx.y * 128, n0 = blockIdx.x * 128;

    f32x4 acc[4][4];
    const f32x4 zero = {0.f, 0.f, 0.f, 0.f};
#pragma unroll
    for (int i = 0; i < 4; ++i)
#pragma unroll
        for (int j = 0; j < 4; ++j) acc[i][j] = zero;

    for (int k0 = 0; k0 < K; k0 += 32) {
        // --- stage A (bf16 direct): 512 chunks of 8 elems ---
#pragma unroll
        for (int i = 0; i < 2; ++i) {
            int c = t + 256 * i;
            int r = c >> 2, col = (c & 3) * 8;
            *(bf16x8*)&As[r][col] =
                *(const bf16x8*)(A + (size_t)(m0 + r) * K + k0 + col);
        }
        // --- stage W ---
        if (wf32) {
            const float* W = (const float*)Wp;
#pragma unroll
            for (int i = 0; i < 4; ++i) {
                int c = t + 256 * i;
                int r = c >> 3, col = (c & 7) * 4;
                float4 wv = *(const float4*)(W + (size_t)(n0 + r) * K + k0 + col);
                bf16x4 p = {tobf(wv.x), tobf(wv.y), tobf(wv.z), tobf(wv.w)};
                *(bf16x4*)&Bs[r][col] = p;
            }
        } else {
            const __bf16* W = (const __bf16*)Wp;
#pragma unroll
            for (int i = 0; i < 2; ++i) {
                int c = t + 256 * i;
                int r = c >> 2, col = (c & 3) * 8;
                *(bf16x8*)&Bs[r][col] =
                    *(const bf16x8*)(W + (size_t)(n0 + r) * K + k0 + col);
            }
        }
        __syncthreads();
        bf16x8 a[4], b[4];
#pragma unroll
        for (int i = 0; i < 4; ++i)
            a[i] = *(const bf16x8*)&As[wm * 64 + i * 16 + lr][lq * 8];
#pragma unroll
        for (int j = 0; j < 4; ++j)
            b[j] = *(const bf16x8*)&Bs[wn * 64 + j * 16 + lr][lq * 8];
#pragma unroll
        for (int i = 0; i < 4; ++i)
#pragma unroll
            for (int j = 0; j < 4; ++j)
                acc[i][j] = __builtin_amdgcn_mfma_f32_16x16x32_bf16(
                    a[i], b[j], acc[i][j], 0, 0, 0);
        __syncthreads();
    }

    // --- epilogue ---
#pragma unroll
    for (int i = 0; i < 4; ++i)
#pragma unroll
        for (int j = 0; j < 4; ++j)
#pragma unroll
            for (int r = 0; r < 4; ++r) {
                int row = m0 + wm * 64 + i * 16 + lq * 4 + r;
                int col = n0 + wn * 64 + j * 16 + lr;
                size_t off = (size_t)row * N + col;
                float v = acc[i][j][r];
                if (EPI == 0) {
                    ((__bf16*)outp)[off] = tobf(v);
                } else if (EPI == 1) {
                    float rv = wf32 ? ((const float*)resp)[off]
                                    : (float)((const __bf16*)resp)[off];
                    ((float*)outp)[off] = rv + v;
                } else if (EPI == 2) {
                    float rv = v > 0.f ? v : 0.f;
                    ((__bf16*)outp)[off] = tobf(rv * rv);
                } else {
                    float rv = ((const float*)resp)[off];
                    float ov = rv + v;
                    if (wf32) ((float*)outp)[off] = ov;
                    else      ((__bf16*)outp)[off] = tobf(ov);
                }
            }
}

// ---------------------------------------------------------------------------
// Causal flash attention. Grid (T/64, H, B), block 256 (4 waves).
// Wave w owns q rows [q0+16w, q0+16w+16). K-block = 64 keys.
__global__ __launch_bounds__(256) void attn_kernel(
    const __bf16* __restrict__ Q, const __bf16* __restrict__ K,
    const __bf16* __restrict__ V, __bf16* __restrict__ O) {
    constexpr int T = 2048, C = 2048, HD = 128;
    __shared__ __bf16 Ks[64][136];     // K rows [tk][d], pitch 136
    __shared__ __bf16 Vt[128][72];     // V transposed [d][tk], pitch 72
    __shared__ __bf16 Ps[4][16][72];   // per-wave P [q][tk]
    const int t = threadIdx.x, w = t >> 6, lane = t & 63;
    const int lr = lane & 15, lq = lane >> 4;
    const int b = blockIdx.z, h = blockIdx.y;
    const int q0 = blockIdx.x * 64;
    const float scale = 0.08838834764831845f;   // 1/sqrt(128)

    // Q fragments live in registers for the whole block (A-operand layout)
    const int qrow = q0 + w * 16 + lr;
    const __bf16* qb = Q + (size_t)(b * T + qrow) * C + h * HD;
    bf16x8 qf[4];
#pragma unroll
    for (int s = 0; s < 4; ++s) qf[s] = *(const bf16x8*)(qb + s * 32 + lq * 8);

    f32x4 oacc[8];
    const f32x4 zero = {0.f, 0.f, 0.f, 0.f};
#pragma unroll
    for (int nc = 0; nc < 8; ++nc) oacc[nc] = zero;
    float m_i[4] = {-3e38f, -3e38f, -3e38f, -3e38f};
    float l_i[4] = {0.f, 0.f, 0.f, 0.f};

    const int nkb = q0 / 64 + 1;   // causal: only k-blocks <= q-block
    for (int kb = 0; kb < nkb; ++kb) {
        const int k00 = kb * 64;
        // stage K rows (coalesced)
#pragma unroll
        for (int i = 0; i < 4; ++i) {
            int c = t + 256 * i;
            int r = c >> 4, col = (c & 15) * 8;
            *(bf16x8*)&Ks[r][col] =
                *(const bf16x8*)(K + (size_t)(b * T + k00 + r) * C + h * HD + col);
        }
        // stage V transposed; lane->row assignment makes LDS writes coalesced
#pragma unroll
        for (int i = 0; i < 4; ++i) {
            int c = t + 256 * i;
            int r = c & 63, col = (c >> 6) * 8;
            bf16x8 vv =
                *(const bf16x8*)(V + (size_t)(b * T + k00 + r) * C + h * HD + col);
#pragma unroll
            for (int j = 0; j < 8; ++j) Vt[col + j][r] = vv[j];
        }
        __syncthreads();

        // S = Q K^T (scaled, masked)
        float pv[4][4];
        float rmax[4] = {-3e38f, -3e38f, -3e38f, -3e38f};
#pragma unroll
        for (int jc = 0; jc < 4; ++jc) {
            f32x4 s = zero;
#pragma unroll
            for (int ks = 0; ks < 4; ++ks) {
                bf16x8 kf = *(const bf16x8*)&Ks[jc * 16 + lr][ks * 32 + lq * 8];
                s = __builtin_amdgcn_mfma_f32_16x16x32_bf16(qf[ks], kf, s, 0, 0, 0);
            }
            int tk = k00 + jc * 16 + lr;
#pragma unroll
            for (int r = 0; r < 4; ++r) {
                int tq = q0 + w * 16 + lq * 4 + r;
                float sv = s[r] * scale;
                sv = (tk > tq) ? -3e38f : sv;
                pv[jc][r] = sv;
                rmax[r] = fmaxf(rmax[r], sv);
            }
        }
        // row-max reduce across the 16 lanes sharing lq
#pragma unroll
        for (int off = 1; off < 16; off <<= 1)
#pragma unroll
            for (int r = 0; r < 4; ++r)
                rmax[r] = fmaxf(rmax[r], __shfl_xor(rmax[r], off));
        float alpha[4], rsum[4] = {0.f, 0.f, 0.f, 0.f};
#pragma unroll
        for (int r = 0; r < 4; ++r) {
            float mn = fmaxf(m_i[r], rmax[r]);
            alpha[r] = __expf(m_i[r] - mn);
            m_i[r] = mn;
        }
#pragma unroll
        for (int jc = 0; jc < 4; ++jc)
#pragma unroll
            for (int r = 0; r < 4; ++r) {
                float p = __expf(pv[jc][r] - m_i[r]);
                rsum[r] += p;
                Ps[w][lq * 4 + r][jc * 16 + lr] = tobf(p);
            }
#pragma unroll
        for (int off = 1; off < 16; off <<= 1)
#pragma unroll
            for (int r = 0; r < 4; ++r) rsum[r] += __shfl_xor(rsum[r], off);
#pragma unroll
        for (int r = 0; r < 4; ++r) l_i[r] = l_i[r] * alpha[r] + rsum[r];
#pragma unroll
        for (int nc = 0; nc < 8; ++nc)
#pragma unroll
            for (int r = 0; r < 4; ++r) oacc[nc][r] *= alpha[r];
        __syncthreads();   // P visible (and ordered) before PV reads

        // O += P V   (P in A-layout from LDS, V^T as B operand)
#pragma unroll
        for (int s2 = 0; s2 < 2; ++s2) {
            bf16x8 pa = *(const bf16x8*)&Ps[w][lr][s2 * 32 + lq * 8];
#pragma unroll
            for (int nc = 0; nc < 8; ++nc) {
                bf16x8 vf = *(const bf16x8*)&Vt[nc * 16 + lr][s2 * 32 + lq * 8];
                oacc[nc] =
                    __builtin_amdgcn_mfma_f32_16x16x32_bf16(pa, vf, oacc[nc], 0, 0, 0);
            }
        }
        __syncthreads();   // PV reads done before next staging overwrite
    }

    // epilogue: normalize by l and store
#pragma unroll
    for (int nc = 0; nc < 8; ++nc)
#pragma unroll
        for (int r = 0; r < 4; ++r) {
            int row = q0 + w * 16 + lq * 4 + r;
            O[(size_t)(b * T + row) * C + h * HD + nc * 16 + lr] =
                tobf(oacc[nc][r] / l_i[r]);
        }
}

// ---------------------------------------------------------------------------
extern "C" void kernel_launch(void* const* d_in, const int* in_sizes, int n_in,
                              void* d_out, int out_size, void* d_ws, size_t ws_size,
                              hipStream_t stream) {
    const void* x   = d_in[0];
    const void* wq  = d_in[1];
    const void* wk  = d_in[2];
    const void* wv  = d_in[3];
    const void* wo  = d_in[4];
    const void* fc1 = d_in[5];
    const void* fc2 = d_in[6];
    constexpr int Bv = 2, Tv = 2048, Cv = 2048, Hv = 16, MLP = 8192;
    constexpr int M = Bv * Tv;                  // 4096 rows
    constexpr size_t NE = (size_t)M * Cv;       // 8,388,608

    char* ws = (char*)d_ws;
    int*    flag = (int*)ws;                    // 256 B reserved
    __bf16* h  = (__bf16*)(ws + 256);           // rmsnorm output (reused for h2)
    __bf16* qb = h  + NE;
    __bf16* kb = qb + NE;
    __bf16* vb = kb + NE;
    __bf16* ao = vb + NE;
    float*  x1 = (float*)(ao + NE);
    __bf16* mm = (__bf16*)(x1 + NE);            // [4096, 8192]
    // total ws use: 256 + 5*16.78MB + 33.55MB + 67.11MB ~= 184.5 MB

    detect_dtype_kernel<<<1, 64, 0, stream>>>((const unsigned short*)x, flag);

    rmsnorm_kernel<0><<<M, 256, 0, stream>>>(x, h, flag);

    dim3 gC(Cv / 128, M / 128);                 // (16, 32)
    gemm_nt<0><<<gC, 256, 0, stream>>>(h, wq, qb, nullptr, M, Cv, Cv, flag);
    gemm_nt<0><<<gC, 256, 0, stream>>>(h, wk, kb, nullptr, M, Cv, Cv, flag);
    gemm_nt<0><<<gC, 256, 0, stream>>>(h, wv, vb, nullptr, M, Cv, Cv, flag);

    attn_kernel<<<dim3(Tv / 64, Hv, Bv), 256, 0, stream>>>(qb, kb, vb, ao);

    gemm_nt<1><<<gC, 256, 0, stream>>>(ao, wo, x1, x, M, Cv, Cv, flag);

    rmsnorm_kernel<1><<<M, 256, 0, stream>>>(x1, h, flag);

    gemm_nt<2><<<dim3(MLP / 128, M / 128), 256, 0, stream>>>(
        h, fc1, mm, nullptr, M, MLP, Cv, flag);

    gemm_nt<3><<<gC, 256, 0, stream>>>(mm, fc2, d_out, x1, M, Cv, MLP, flag);
}

// Round 2
// 1327.375 us; speedup vs baseline: 1.2407x; 1.2407x over previous
//
#include <hip/hip_runtime.h>

// ---------------------------------------------------------------------------
// TransformerBlock: B=2 T=2048 C=2048 H=16 HD=128 MLP=8192, causal, relu^2 MLP
// Round 2: m97-style GEMM — global_load_lds width=16, unpadded LDS tiles.
//
// mfma_f32_16x16x32_bf16 layouts (learn_hip m89/m91):
//   A[m=lane&15][k=(lane>>4)*8+j], B[n=lane&15][k=(lane>>4)*8+j]
//   D[row=(lane>>4)*4+reg][col=lane&15]
// ---------------------------------------------------------------------------

typedef __bf16 bf16x8 __attribute__((ext_vector_type(8)));
typedef __bf16 bf16x4 __attribute__((ext_vector_type(4)));
typedef float  f32x4  __attribute__((ext_vector_type(4)));

static __device__ __forceinline__ __bf16 tobf(float f) { return (__bf16)f; }

// async 16B global->LDS. lptr must be wave-uniform; HW writes lane l at
// lptr + l*16 (cdna_hip_programming.md §5 caveat).
static __device__ __forceinline__ void async_copy16(const void* g, void* l) {
    __builtin_amdgcn_global_load_lds(
        (const __attribute__((address_space(1))) void*)g,
        (__attribute__((address_space(3))) void*)l, 16, 0, 0);
}

// ---------------------------------------------------------------------------
__global__ void detect_dtype_kernel(const unsigned short* __restrict__ xh,
                                    int* __restrict__ flag) {
    int t = threadIdx.x;                       // one wave of 64
    unsigned short u = xh[2 * t];              // even ushort slots
    int e = (u >> 7) & 0xFF;                   // bf16 exponent field
    bool outlier = (e < 100) || (e > 131);     // implausible for N(0,1)
    unsigned long long m = __ballot(outlier);
    if (t == 0) *flag = (__popcll(m) >= 16) ? 1 : 0;   // 1 => fp32 buffers
}

// ---------------------------------------------------------------------------
// rmsnorm: row of C=2048, one block per row, 256 threads x 8 elements.
template <int SRC>
__global__ __launch_bounds__(256) void rmsnorm_kernel(
    const void* __restrict__ xp, __bf16* __restrict__ h,
    const int* __restrict__ flagp) {
    constexpr int C = 2048;
    const int row = blockIdx.x, t = threadIdx.x;
    float vals[8];
    bool f32in = (SRC == 1) || (*flagp != 0);
    if (f32in) {
        const float4* xr = (const float4*)((const float*)xp + (size_t)row * C);
        float4 a = xr[2 * t], b = xr[2 * t + 1];
        vals[0] = a.x; vals[1] = a.y; vals[2] = a.z; vals[3] = a.w;
        vals[4] = b.x; vals[5] = b.y; vals[6] = b.z; vals[7] = b.w;
    } else {
        bf16x8 a = *((const bf16x8*)((const __bf16*)xp + (size_t)row * C) + t);
#pragma unroll
        for (int j = 0; j < 8; ++j) vals[j] = (float)a[j];
    }
    float ss = 0.f;
#pragma unroll
    for (int j = 0; j < 8; ++j) ss += vals[j] * vals[j];
#pragma unroll
    for (int off = 32; off > 0; off >>= 1) ss += __shfl_down(ss, off);
    __shared__ float red[4];
    if ((t & 63) == 0) red[t >> 6] = ss;
    __syncthreads();
    float mean = (red[0] + red[1] + red[2] + red[3]) * (1.0f / C);
    float sc = rsqrtf(mean + 1e-5f);
    bf16x8 o;
#pragma unroll
    for (int j = 0; j < 8; ++j) o[j] = tobf(vals[j] * sc);
    *((bf16x8*)(h + (size_t)row * C) + t) = o;
}

// ---------------------------------------------------------------------------
// NT GEMM: out[M,N] = A[M,K](bf16) @ W[N,K]^T (+epilogue)
// 128x128 tile, BK=32, 4 waves (2x2), each wave 64x64 via 4x4 mfma 16x16x32.
// LDS tiles are UNPADDED [128][32] so global_load_lds lane order == layout
// (chunk c = t covers row c>>2, 8-elem group c&3; LDS byte offset = c*16).
// EPI 0: store bf16 | 1: fp32 out = res + acc | 2: bf16 relu(acc)^2
// EPI 3: out(dtype per flag) = res(fp32) + acc
template <int EPI>
__global__ __launch_bounds__(256) void gemm_nt(
    const __bf16* __restrict__ A, const void* __restrict__ Wp,
    void* __restrict__ outp, const void* __restrict__ resp,
    int M, int N, int K, const int* __restrict__ flagp) {
    __shared__ __bf16 As[128][32];
    __shared__ __bf16 Bs[128][32];
    const bool wf32 = (*flagp != 0);
    const int t = threadIdx.x;
    const int wave = t >> 6, lane = t & 63;
    const int lr = lane & 15, lq = lane >> 4;
    const int wm = wave & 1, wn = wave >> 1;
    const int m0 = blockIdx.y * 128, n0 = blockIdx.x * 128;

    // hoisted per-thread staging pointers (chunks c0 = t, c1 = t + 256)
    const int r0 = t >> 2, col0 = (t & 3) * 8;
    const int r1 = (t + 256) >> 2, col1 = col0;          // (t+256)&3 == t&3
    const __bf16* gA0 = A + (size_t)(m0 + r0) * K + col0;
    const __bf16* gA1 = A + (size_t)(m0 + r1) * K + col1;
    const __bf16* gB0 = (const __bf16*)Wp + (size_t)(n0 + r0) * K + col0;
    const __bf16* gB1 = (const __bf16*)Wp + (size_t)(n0 + r1) * K + col1;
    // wave-uniform LDS bases (chunk base = issue*256 + wave*64, *8 elems)
    __bf16* lA0 = &As[0][0] + (size_t)(wave * 64) * 8;
    __bf16* lA1 = &As[0][0] + (size_t)(256 + wave * 64) * 8;
    __bf16* lB0 = &Bs[0][0] + (size_t)(wave * 64) * 8;
    __bf16* lB1 = &Bs[0][0] + (size_t)(256 + wave * 64) * 8;

    f32x4 acc[4][4];
    const f32x4 zero = {0.f, 0.f, 0.f, 0.f};
#pragma unroll
    for (int i = 0; i < 4; ++i)
#pragma unroll
        for (int j = 0; j < 4; ++j) acc[i][j] = zero;

    for (int k0 = 0; k0 < K; k0 += 32) {
        async_copy16(gA0 + k0, lA0);
        async_copy16(gA1 + k0, lA1);
        if (!wf32) {
            async_copy16(gB0 + k0, lB0);
            async_copy16(gB1 + k0, lB1);
        } else {
            const float* W = (const float*)Wp;
#pragma unroll
            for (int i = 0; i < 2; ++i) {
                int c = t + 256 * i;
                int r = c >> 2, col = (c & 3) * 8;
                float4 wa = *(const float4*)(W + (size_t)(n0 + r) * K + k0 + col);
                float4 wb = *(const float4*)(W + (size_t)(n0 + r) * K + k0 + col + 4);
                bf16x8 p = {tobf(wa.x), tobf(wa.y), tobf(wa.z), tobf(wa.w),
                            tobf(wb.x), tobf(wb.y), tobf(wb.z), tobf(wb.w)};
                *(bf16x8*)&Bs[r][col] = p;
            }
        }
        __syncthreads();    // drains vmcnt (global_load_lds) + lds writes
        bf16x8 a[4], b[4];
#pragma unroll
        for (int i = 0; i < 4; ++i)
            a[i] = *(const bf16x8*)&As[wm * 64 + i * 16 + lr][lq * 8];
#pragma unroll
        for (int j = 0; j < 4; ++j)
            b[j] = *(const bf16x8*)&Bs[wn * 64 + j * 16 + lr][lq * 8];
#pragma unroll
        for (int i = 0; i < 4; ++i)
#pragma unroll
            for (int j = 0; j < 4; ++j)
                acc[i][j] = __builtin_amdgcn_mfma_f32_16x16x32_bf16(
                    a[i], b[j], acc[i][j], 0, 0, 0);
        __syncthreads();
    }

    // --- epilogue ---
#pragma unroll
    for (int i = 0; i < 4; ++i)
#pragma unroll
        for (int j = 0; j < 4; ++j)
#pragma unroll
            for (int r = 0; r < 4; ++r) {
                int row = m0 + wm * 64 + i * 16 + lq * 4 + r;
                int col = n0 + wn * 64 + j * 16 + lr;
                size_t off = (size_t)row * N + col;
                float v = acc[i][j][r];
                if (EPI == 0) {
                    ((__bf16*)outp)[off] = tobf(v);
                } else if (EPI == 1) {
                    float rv = wf32 ? ((const float*)resp)[off]
                                    : (float)((const __bf16*)resp)[off];
                    ((float*)outp)[off] = rv + v;
                } else if (EPI == 2) {
                    float rv = v > 0.f ? v : 0.f;
                    ((__bf16*)outp)[off] = tobf(rv * rv);
                } else {
                    float rv = ((const float*)resp)[off];
                    float ov = rv + v;
                    if (wf32) ((float*)outp)[off] = ov;
                    else      ((__bf16*)outp)[off] = tobf(ov);
                }
            }
}

// ---------------------------------------------------------------------------
// Causal flash attention. Grid (T/64, H, B), block 256 (4 waves).
// Wave w owns q rows [q0+16w, q0+16w+16). K-block = 64 keys.
__global__ __launch_bounds__(256) void attn_kernel(
    const __bf16* __restrict__ Q, const __bf16* __restrict__ K,
    const __bf16* __restrict__ V, __bf16* __restrict__ O) {
    constexpr int T = 2048, C = 2048, HD = 128;
    __shared__ __bf16 Ks[64][136];     // K rows [tk][d], pitch 136
    __shared__ __bf16 Vt[128][72];     // V transposed [d][tk], pitch 72
    __shared__ __bf16 Ps[4][16][72];   // per-wave P [q][tk]
    const int t = threadIdx.x, w = t >> 6, lane = t & 63;
    const int lr = lane & 15, lq = lane >> 4;
    const int b = blockIdx.z, h = blockIdx.y;
    const int q0 = blockIdx.x * 64;
    const float scale = 0.08838834764831845f;   // 1/sqrt(128)

    const int qrow = q0 + w * 16 + lr;
    const __bf16* qb = Q + (size_t)(b * T + qrow) * C + h * HD;
    bf16x8 qf[4];
#pragma unroll
    for (int s = 0; s < 4; ++s) qf[s] = *(const bf16x8*)(qb + s * 32 + lq * 8);

    f32x4 oacc[8];
    const f32x4 zero = {0.f, 0.f, 0.f, 0.f};
#pragma unroll
    for (int nc = 0; nc < 8; ++nc) oacc[nc] = zero;
    float m_i[4] = {-3e38f, -3e38f, -3e38f, -3e38f};
    float l_i[4] = {0.f, 0.f, 0.f, 0.f};

    const int nkb = q0 / 64 + 1;   // causal: only k-blocks <= q-block
    for (int kb = 0; kb < nkb; ++kb) {
        const int k00 = kb * 64;
#pragma unroll
        for (int i = 0; i < 4; ++i) {
            int c = t + 256 * i;
            int r = c >> 4, col = (c & 15) * 8;
            *(bf16x8*)&Ks[r][col] =
                *(const bf16x8*)(K + (size_t)(b * T + k00 + r) * C + h * HD + col);
        }
#pragma unroll
        for (int i = 0; i < 4; ++i) {
            int c = t + 256 * i;
            int r = c & 63, col = (c >> 6) * 8;
            bf16x8 vv =
                *(const bf16x8*)(V + (size_t)(b * T + k00 + r) * C + h * HD + col);
#pragma unroll
            for (int j = 0; j < 8; ++j) Vt[col + j][r] = vv[j];
        }
        __syncthreads();

        float pv[4][4];
        float rmax[4] = {-3e38f, -3e38f, -3e38f, -3e38f};
#pragma unroll
        for (int jc = 0; jc < 4; ++jc) {
            f32x4 s = zero;
#pragma unroll
            for (int ks = 0; ks < 4; ++ks) {
                bf16x8 kf = *(const bf16x8*)&Ks[jc * 16 + lr][ks * 32 + lq * 8];
                s = __builtin_amdgcn_mfma_f32_16x16x32_bf16(qf[ks], kf, s, 0, 0, 0);
            }
            int tk = k00 + jc * 16 + lr;
#pragma unroll
            for (int r = 0; r < 4; ++r) {
                int tq = q0 + w * 16 + lq * 4 + r;
                float sv = s[r] * scale;
                sv = (tk > tq) ? -3e38f : sv;
                pv[jc][r] = sv;
                rmax[r] = fmaxf(rmax[r], sv);
            }
        }
#pragma unroll
        for (int off = 1; off < 16; off <<= 1)
#pragma unroll
            for (int r = 0; r < 4; ++r)
                rmax[r] = fmaxf(rmax[r], __shfl_xor(rmax[r], off));
        float alpha[4], rsum[4] = {0.f, 0.f, 0.f, 0.f};
#pragma unroll
        for (int r = 0; r < 4; ++r) {
            float mn = fmaxf(m_i[r], rmax[r]);
            alpha[r] = __expf(m_i[r] - mn);
            m_i[r] = mn;
        }
#pragma unroll
        for (int jc = 0; jc < 4; ++jc)
#pragma unroll
            for (int r = 0; r < 4; ++r) {
                float p = __expf(pv[jc][r] - m_i[r]);
                rsum[r] += p;
                Ps[w][lq * 4 + r][jc * 16 + lr] = tobf(p);
            }
#pragma unroll
        for (int off = 1; off < 16; off <<= 1)
#pragma unroll
            for (int r = 0; r < 4; ++r) rsum[r] += __shfl_xor(rsum[r], off);
#pragma unroll
        for (int r = 0; r < 4; ++r) l_i[r] = l_i[r] * alpha[r] + rsum[r];
#pragma unroll
        for (int nc = 0; nc < 8; ++nc)
#pragma unroll
            for (int r = 0; r < 4; ++r) oacc[nc][r] *= alpha[r];
        __syncthreads();

#pragma unroll
        for (int s2 = 0; s2 < 2; ++s2) {
            bf16x8 pa = *(const bf16x8*)&Ps[w][lr][s2 * 32 + lq * 8];
#pragma unroll
            for (int nc = 0; nc < 8; ++nc) {
                bf16x8 vf = *(const bf16x8*)&Vt[nc * 16 + lr][s2 * 32 + lq * 8];
                oacc[nc] =
                    __builtin_amdgcn_mfma_f32_16x16x32_bf16(pa, vf, oacc[nc], 0, 0, 0);
            }
        }
        __syncthreads();
    }

#pragma unroll
    for (int nc = 0; nc < 8; ++nc)
#pragma unroll
        for (int r = 0; r < 4; ++r) {
            int row = q0 + w * 16 + lq * 4 + r;
            O[(size_t)(b * T + row) * C + h * HD + nc * 16 + lr] =
                tobf(oacc[nc][r] / l_i[r]);
        }
}

// ---------------------------------------------------------------------------
extern "C" void kernel_launch(void* const* d_in, const int* in_sizes, int n_in,
                              void* d_out, int out_size, void* d_ws, size_t ws_size,
                              hipStream_t stream) {
    const void* x   = d_in[0];
    const void* wq  = d_in[1];
    const void* wk  = d_in[2];
    const void* wv  = d_in[3];
    const void* wo  = d_in[4];
    const void* fc1 = d_in[5];
    const void* fc2 = d_in[6];
    constexpr int Bv = 2, Tv = 2048, Cv = 2048, Hv = 16, MLP = 8192;
    constexpr int M = Bv * Tv;                  // 4096 rows
    constexpr size_t NE = (size_t)M * Cv;       // 8,388,608

    char* ws = (char*)d_ws;
    int*    flag = (int*)ws;                    // 256 B reserved
    __bf16* h  = (__bf16*)(ws + 256);           // rmsnorm output (reused for h2)
    __bf16* qb = h  + NE;
    __bf16* kb = qb + NE;
    __bf16* vb = kb + NE;
    __bf16* ao = vb + NE;
    float*  x1 = (float*)(ao + NE);
    __bf16* mm = (__bf16*)(x1 + NE);            // [4096, 8192]

    detect_dtype_kernel<<<1, 64, 0, stream>>>((const unsigned short*)x, flag);

    rmsnorm_kernel<0><<<M, 256, 0, stream>>>(x, h, flag);

    dim3 gC(Cv / 128, M / 128);                 // (16, 32)
    gemm_nt<0><<<gC, 256, 0, stream>>>(h, wq, qb, nullptr, M, Cv, Cv, flag);
    gemm_nt<0><<<gC, 256, 0, stream>>>(h, wk, kb, nullptr, M, Cv, Cv, flag);
    gemm_nt<0><<<gC, 256, 0, stream>>>(h, wv, vb, nullptr, M, Cv, Cv, flag);

    attn_kernel<<<dim3(Tv / 64, Hv, Bv), 256, 0, stream>>>(qb, kb, vb, ao);

    gemm_nt<1><<<gC, 256, 0, stream>>>(ao, wo, x1, x, M, Cv, Cv, flag);

    rmsnorm_kernel<1><<<M, 256, 0, stream>>>(x1, h, flag);

    gemm_nt<2><<<dim3(MLP / 128, M / 128), 256, 0, stream>>>(
        h, fc1, mm, nullptr, M, MLP, Cv, flag);

    gemm_nt<3><<<gC, 256, 0, stream>>>(mm, fc2, d_out, x1, M, Cv, MLP, flag);
}

// Round 3
// 1153.599 us; speedup vs baseline: 1.4276x; 1.1506x over previous
//
#include <hip/hip_runtime.h>

// ---------------------------------------------------------------------------
// TransformerBlock: B=2 T=2048 C=2048 H=16 HD=128 MLP=8192, causal, relu^2 MLP
// Round 3: occupancy fixes — fused QKV (1536 blocks), split-K=2 for wo/fc2
// (1024 blocks + reduce), V produced pre-transposed for attention.
//
// mfma_f32_16x16x32_bf16 layouts (learn_hip m89/m91):
//   A[m=lane&15][k=(lane>>4)*8+j], B[n=lane&15][k=(lane>>4)*8+j]
//   D[row=(lane>>4)*4+reg][col=lane&15]
// ---------------------------------------------------------------------------

typedef __bf16 bf16x8 __attribute__((ext_vector_type(8)));
typedef __bf16 bf16x4 __attribute__((ext_vector_type(4)));
typedef float  f32x4  __attribute__((ext_vector_type(4)));

static __device__ __forceinline__ __bf16 tobf(float f) { return (__bf16)f; }

// async 16B global->LDS; lptr wave-uniform, HW writes lane l at lptr + l*16.
static __device__ __forceinline__ void async_copy16(const void* g, void* l) {
    __builtin_amdgcn_global_load_lds(
        (const __attribute__((address_space(1))) void*)g,
        (__attribute__((address_space(3))) void*)l, 16, 0, 0);
}

// ---------------------------------------------------------------------------
__global__ void detect_dtype_kernel(const unsigned short* __restrict__ xh,
                                    int* __restrict__ flag) {
    int t = threadIdx.x;                       // one wave of 64
    unsigned short u = xh[2 * t];              // even ushort slots
    int e = (u >> 7) & 0xFF;                   // bf16 exponent field
    bool outlier = (e < 100) || (e > 131);     // implausible for N(0,1)
    unsigned long long m = __ballot(outlier);
    if (t == 0) *flag = (__popcll(m) >= 16) ? 1 : 0;   // 1 => fp32 buffers
}

// ---------------------------------------------------------------------------
// rmsnorm: row of C=2048, one block per row, 256 threads x 8 elements.
template <int SRC>
__global__ __launch_bounds__(256) void rmsnorm_kernel(
    const void* __restrict__ xp, __bf16* __restrict__ h,
    const int* __restrict__ flagp) {
    constexpr int C = 2048;
    const int row = blockIdx.x, t = threadIdx.x;
    float vals[8];
    bool f32in = (SRC == 1) || (*flagp != 0);
    if (f32in) {
        const float4* xr = (const float4*)((const float*)xp + (size_t)row * C);
        float4 a = xr[2 * t], b = xr[2 * t + 1];
        vals[0] = a.x; vals[1] = a.y; vals[2] = a.z; vals[3] = a.w;
        vals[4] = b.x; vals[5] = b.y; vals[6] = b.z; vals[7] = b.w;
    } else {
        bf16x8 a = *((const bf16x8*)((const __bf16*)xp + (size_t)row * C) + t);
#pragma unroll
        for (int j = 0; j < 8; ++j) vals[j] = (float)a[j];
    }
    float ss = 0.f;
#pragma unroll
    for (int j = 0; j < 8; ++j) ss += vals[j] * vals[j];
#pragma unroll
    for (int off = 32; off > 0; off >>= 1) ss += __shfl_down(ss, off);
    __shared__ float red[4];
    if ((t & 63) == 0) red[t >> 6] = ss;
    __syncthreads();
    float mean = (red[0] + red[1] + red[2] + red[3]) * (1.0f / C);
    float sc = rsqrtf(mean + 1e-5f);
    bf16x8 o;
#pragma unroll
    for (int j = 0; j < 8; ++j) o[j] = tobf(vals[j] * sc);
    *((bf16x8*)(h + (size_t)row * C) + t) = o;
}

// ---------------------------------------------------------------------------
// NT GEMM: out = A[M,K](bf16) @ W[N,K]^T. 128x128 tile, BK=32, 4 waves.
// gridDim.z = split-K count (K/gridDim.z per slice).
// EPI 2: bf16 relu(acc)^2  (fc1)
// EPI 4: fp32 partial store at outp + blockIdx.z*M*N  (split-K)
template <int EPI>
__global__ __launch_bounds__(256) void gemm_nt(
    const __bf16* __restrict__ A, const void* __restrict__ Wp,
    void* __restrict__ outp, int M, int N, int K,
    const int* __restrict__ flagp) {
    __shared__ __align__(16) __bf16 As[128][32];
    __shared__ __align__(16) __bf16 Bs[128][32];
    const bool wf32 = (*flagp != 0);
    const int t = threadIdx.x;
    const int wave = t >> 6, lane = t & 63;
    const int lr = lane & 15, lq = lane >> 4;
    const int wm = wave & 1, wn = wave >> 1;
    const int m0 = blockIdx.y * 128, n0 = blockIdx.x * 128;
    const int kz = K / gridDim.z;
    const int kbeg = blockIdx.z * kz, kend = kbeg + kz;

    const int r0 = t >> 2, col0 = (t & 3) * 8;
    const int r1 = (t + 256) >> 2;
    const __bf16* gA0 = A + (size_t)(m0 + r0) * K + col0;
    const __bf16* gA1 = A + (size_t)(m0 + r1) * K + col0;
    const __bf16* gB0 = (const __bf16*)Wp + (size_t)(n0 + r0) * K + col0;
    const __bf16* gB1 = (const __bf16*)Wp + (size_t)(n0 + r1) * K + col0;
    __bf16* lA0 = &As[0][0] + (size_t)(wave * 64) * 8;
    __bf16* lA1 = &As[0][0] + (size_t)(256 + wave * 64) * 8;
    __bf16* lB0 = &Bs[0][0] + (size_t)(wave * 64) * 8;
    __bf16* lB1 = &Bs[0][0] + (size_t)(256 + wave * 64) * 8;

    f32x4 acc[4][4];
    const f32x4 zero = {0.f, 0.f, 0.f, 0.f};
#pragma unroll
    for (int i = 0; i < 4; ++i)
#pragma unroll
        for (int j = 0; j < 4; ++j) acc[i][j] = zero;

    for (int k0 = kbeg; k0 < kend; k0 += 32) {
        async_copy16(gA0 + k0, lA0);
        async_copy16(gA1 + k0, lA1);
        if (!wf32) {
            async_copy16(gB0 + k0, lB0);
            async_copy16(gB1 + k0, lB1);
        } else {
            const float* W = (const float*)Wp;
#pragma unroll
            for (int i = 0; i < 2; ++i) {
                int c = t + 256 * i;
                int r = c >> 2, col = (c & 3) * 8;
                float4 wa = *(const float4*)(W + (size_t)(n0 + r) * K + k0 + col);
                float4 wb = *(const float4*)(W + (size_t)(n0 + r) * K + k0 + col + 4);
                bf16x8 p = {tobf(wa.x), tobf(wa.y), tobf(wa.z), tobf(wa.w),
                            tobf(wb.x), tobf(wb.y), tobf(wb.z), tobf(wb.w)};
                *(bf16x8*)&Bs[r][col] = p;
            }
        }
        __syncthreads();
        bf16x8 a[4], b[4];
#pragma unroll
        for (int i = 0; i < 4; ++i)
            a[i] = *(const bf16x8*)&As[wm * 64 + i * 16 + lr][lq * 8];
#pragma unroll
        for (int j = 0; j < 4; ++j)
            b[j] = *(const bf16x8*)&Bs[wn * 64 + j * 16 + lr][lq * 8];
#pragma unroll
        for (int i = 0; i < 4; ++i)
#pragma unroll
            for (int j = 0; j < 4; ++j)
                acc[i][j] = __builtin_amdgcn_mfma_f32_16x16x32_bf16(
                    a[i], b[j], acc[i][j], 0, 0, 0);
        __syncthreads();
    }

    const size_t pbase = (size_t)blockIdx.z * ((size_t)M * N);
#pragma unroll
    for (int i = 0; i < 4; ++i)
#pragma unroll
        for (int j = 0; j < 4; ++j)
#pragma unroll
            for (int r = 0; r < 4; ++r) {
                int row = m0 + wm * 64 + i * 16 + lq * 4 + r;
                int col = n0 + wn * 64 + j * 16 + lr;
                size_t off = (size_t)row * N + col;
                float v = acc[i][j][r];
                if (EPI == 2) {
                    float rv = v > 0.f ? v : 0.f;
                    ((__bf16*)outp)[off] = tobf(rv * rv);
                } else {
                    ((float*)outp)[pbase + off] = v;
                }
            }
}

// ---------------------------------------------------------------------------
// Fused QKV GEMM: grid (48, 32). which = bx>>4 selects weight/output.
// V output (which==2) is stored TRANSPOSED: Vt[(b*2048 + col)*2048 + t]
// (col = h*128+d), so attention can stage V^T tiles with vector loads.
__global__ __launch_bounds__(256) void gemm_qkv(
    const __bf16* __restrict__ A, const void* __restrict__ wqp,
    const void* __restrict__ wkp, const void* __restrict__ wvp,
    __bf16* __restrict__ qout, __bf16* __restrict__ kout,
    __bf16* __restrict__ vtout, const int* __restrict__ flagp) {
    constexpr int N = 2048, K = 2048;
    __shared__ __align__(16) __bf16 As[128][32];
    __shared__ __align__(16) __bf16 Bs[128][32];
    const bool wf32 = (*flagp != 0);
    const int t = threadIdx.x;
    const int wave = t >> 6, lane = t & 63;
    const int lr = lane & 15, lq = lane >> 4;
    const int wm = wave & 1, wn = wave >> 1;
    const int which = blockIdx.x >> 4;
    const int m0 = blockIdx.y * 128, n0 = (blockIdx.x & 15) * 128;
    const void* Wp = (which == 0) ? wqp : (which == 1) ? wkp : wvp;

    const int r0 = t >> 2, col0 = (t & 3) * 8;
    const int r1 = (t + 256) >> 2;
    const __bf16* gA0 = A + (size_t)(m0 + r0) * K + col0;
    const __bf16* gA1 = A + (size_t)(m0 + r1) * K + col0;
    const __bf16* gB0 = (const __bf16*)Wp + (size_t)(n0 + r0) * K + col0;
    const __bf16* gB1 = (const __bf16*)Wp + (size_t)(n0 + r1) * K + col0;
    __bf16* lA0 = &As[0][0] + (size_t)(wave * 64) * 8;
    __bf16* lA1 = &As[0][0] + (size_t)(256 + wave * 64) * 8;
    __bf16* lB0 = &Bs[0][0] + (size_t)(wave * 64) * 8;
    __bf16* lB1 = &Bs[0][0] + (size_t)(256 + wave * 64) * 8;

    f32x4 acc[4][4];
    const f32x4 zero = {0.f, 0.f, 0.f, 0.f};
#pragma unroll
    for (int i = 0; i < 4; ++i)
#pragma unroll
        for (int j = 0; j < 4; ++j) acc[i][j] = zero;

    for (int k0 = 0; k0 < K; k0 += 32) {
        async_copy16(gA0 + k0, lA0);
        async_copy16(gA1 + k0, lA1);
        if (!wf32) {
            async_copy16(gB0 + k0, lB0);
            async_copy16(gB1 + k0, lB1);
        } else {
            const float* W = (const float*)Wp;
#pragma unroll
            for (int i = 0; i < 2; ++i) {
                int c = t + 256 * i;
                int r = c >> 2, col = (c & 3) * 8;
                float4 wa = *(const float4*)(W + (size_t)(n0 + r) * K + k0 + col);
                float4 wb = *(const float4*)(W + (size_t)(n0 + r) * K + k0 + col + 4);
                bf16x8 p = {tobf(wa.x), tobf(wa.y), tobf(wa.z), tobf(wa.w),
                            tobf(wb.x), tobf(wb.y), tobf(wb.z), tobf(wb.w)};
                *(bf16x8*)&Bs[r][col] = p;
            }
        }
        __syncthreads();
        bf16x8 a[4], b[4];
#pragma unroll
        for (int i = 0; i < 4; ++i)
            a[i] = *(const bf16x8*)&As[wm * 64 + i * 16 + lr][lq * 8];
#pragma unroll
        for (int j = 0; j < 4; ++j)
            b[j] = *(const bf16x8*)&Bs[wn * 64 + j * 16 + lr][lq * 8];
#pragma unroll
        for (int i = 0; i < 4; ++i)
#pragma unroll
            for (int j = 0; j < 4; ++j)
                acc[i][j] = __builtin_amdgcn_mfma_f32_16x16x32_bf16(
                    a[i], b[j], acc[i][j], 0, 0, 0);
        __syncthreads();
    }

    if (which < 2) {
        __bf16* outp = (which == 0) ? qout : kout;
#pragma unroll
        for (int i = 0; i < 4; ++i)
#pragma unroll
            for (int j = 0; j < 4; ++j)
#pragma unroll
                for (int r = 0; r < 4; ++r) {
                    int row = m0 + wm * 64 + i * 16 + lq * 4 + r;
                    int col = n0 + wn * 64 + j * 16 + lr;
                    outp[(size_t)row * N + col] = tobf(acc[i][j][r]);
                }
    } else {
#pragma unroll
        for (int i = 0; i < 4; ++i)
#pragma unroll
            for (int j = 0; j < 4; ++j) {
                int t0 = m0 + wm * 64 + i * 16 + lq * 4;   // token index (4 consec)
                int b  = t0 >> 11, tt = t0 & 2047;
                int col = n0 + wn * 64 + j * 16 + lr;      // h*128 + d
                bf16x4 p = {tobf(acc[i][j][0]), tobf(acc[i][j][1]),
                            tobf(acc[i][j][2]), tobf(acc[i][j][3])};
                *(bf16x4*)(vtout + (((size_t)(b * 2048 + col)) << 11) + tt) = p;
            }
    }
}

// ---------------------------------------------------------------------------
// Split-K reduce + residual.
// MODE 0: out fp32 = res(dtype per flag) + p0 + p1          (wo -> x1)
// MODE 1: out(dtype per flag) = res(fp32) + p0 + p1         (fc2 -> d_out)
template <int MODE>
__global__ __launch_bounds__(256) void reduce_kernel(
    const float* __restrict__ p0, const float* __restrict__ p1,
    const void* __restrict__ resp, void* __restrict__ outp,
    const int* __restrict__ flagp) {
    const bool f32 = (*flagp != 0);
    size_t i = ((size_t)blockIdx.x * 256 + threadIdx.x) * 4;
    float4 a = *(const float4*)(p0 + i);
    float4 b = *(const float4*)(p1 + i);
    float rx, ry, rz, rw;
    if (MODE == 1 || f32) {
        float4 r = *(const float4*)((const float*)resp + i);
        rx = r.x; ry = r.y; rz = r.z; rw = r.w;
    } else {
        bf16x4 rb = *(const bf16x4*)((const __bf16*)resp + i);
        rx = (float)rb[0]; ry = (float)rb[1]; rz = (float)rb[2]; rw = (float)rb[3];
    }
    float ox = rx + a.x + b.x, oy = ry + a.y + b.y;
    float oz = rz + a.z + b.z, ow = rw + a.w + b.w;
    if (MODE == 0 || f32) {
        float4 o = {ox, oy, oz, ow};
        *(float4*)((float*)outp + i) = o;
    } else {
        bf16x4 o = {tobf(ox), tobf(oy), tobf(oz), tobf(ow)};
        *(bf16x4*)((__bf16*)outp + i) = o;
    }
}

// ---------------------------------------------------------------------------
// Causal flash attention. Grid (T/64, H, B), block 256 (4 waves).
// V comes in pre-transposed: Vt[(b*2048 + h*128 + d)*2048 + t].
__global__ __launch_bounds__(256) void attn_kernel(
    const __bf16* __restrict__ Q, const __bf16* __restrict__ K,
    const __bf16* __restrict__ Vt, __bf16* __restrict__ O) {
    constexpr int T = 2048, C = 2048, HD = 128;
    __shared__ __align__(16) __bf16 Ks[64][136];
    __shared__ __align__(16) __bf16 Vts[128][72];
    __shared__ __align__(16) __bf16 Ps[4][16][72];
    const int t = threadIdx.x, w = t >> 6, lane = t & 63;
    const int lr = lane & 15, lq = lane >> 4;
    const int b = blockIdx.z, h = blockIdx.y;
    const int q0 = blockIdx.x * 64;
    const float scale = 0.08838834764831845f;   // 1/sqrt(128)

    const int qrow = q0 + w * 16 + lr;
    const __bf16* qb = Q + (size_t)(b * T + qrow) * C + h * HD;
    bf16x8 qf[4];
#pragma unroll
    for (int s = 0; s < 4; ++s) qf[s] = *(const bf16x8*)(qb + s * 32 + lq * 8);
    const __bf16* vtb = Vt + ((size_t)(b * 2048 + h * 128) << 11);

    f32x4 oacc[8];
    const f32x4 zero = {0.f, 0.f, 0.f, 0.f};
#pragma unroll
    for (int nc = 0; nc < 8; ++nc) oacc[nc] = zero;
    float m_i[4] = {-3e38f, -3e38f, -3e38f, -3e38f};
    float l_i[4] = {0.f, 0.f, 0.f, 0.f};

    const int nkb = q0 / 64 + 1;
    for (int kb = 0; kb < nkb; ++kb) {
        const int k00 = kb * 64;
#pragma unroll
        for (int i = 0; i < 4; ++i) {
            int c = t + 256 * i;
            int r = c >> 4, col = (c & 15) * 8;
            *(bf16x8*)&Ks[r][col] =
                *(const bf16x8*)(K + (size_t)(b * T + k00 + r) * C + h * HD + col);
        }
#pragma unroll
        for (int i = 0; i < 4; ++i) {
            int c = t + 256 * i;
            int r = c >> 3, cg = (c & 7) * 8;
            *(bf16x8*)&Vts[r][cg] =
                *(const bf16x8*)(vtb + ((size_t)r << 11) + k00 + cg);
        }
        __syncthreads();

        float pv[4][4];
        float rmax[4] = {-3e38f, -3e38f, -3e38f, -3e38f};
#pragma unroll
        for (int jc = 0; jc < 4; ++jc) {
            f32x4 s = zero;
#pragma unroll
            for (int ks = 0; ks < 4; ++ks) {
                bf16x8 kf = *(const bf16x8*)&Ks[jc * 16 + lr][ks * 32 + lq * 8];
                s = __builtin_amdgcn_mfma_f32_16x16x32_bf16(qf[ks], kf, s, 0, 0, 0);
            }
            int tk = k00 + jc * 16 + lr;
#pragma unroll
            for (int r = 0; r < 4; ++r) {
                int tq = q0 + w * 16 + lq * 4 + r;
                float sv = s[r] * scale;
                sv = (tk > tq) ? -3e38f : sv;
                pv[jc][r] = sv;
                rmax[r] = fmaxf(rmax[r], sv);
            }
        }
#pragma unroll
        for (int off = 1; off < 16; off <<= 1)
#pragma unroll
            for (int r = 0; r < 4; ++r)
                rmax[r] = fmaxf(rmax[r], __shfl_xor(rmax[r], off));
        float alpha[4], rsum[4] = {0.f, 0.f, 0.f, 0.f};
#pragma unroll
        for (int r = 0; r < 4; ++r) {
            float mn = fmaxf(m_i[r], rmax[r]);
            alpha[r] = __expf(m_i[r] - mn);
            m_i[r] = mn;
        }
#pragma unroll
        for (int jc = 0; jc < 4; ++jc)
#pragma unroll
            for (int r = 0; r < 4; ++r) {
                float p = __expf(pv[jc][r] - m_i[r]);
                rsum[r] += p;
                Ps[w][lq * 4 + r][jc * 16 + lr] = tobf(p);
            }
#pragma unroll
        for (int off = 1; off < 16; off <<= 1)
#pragma unroll
            for (int r = 0; r < 4; ++r) rsum[r] += __shfl_xor(rsum[r], off);
#pragma unroll
        for (int r = 0; r < 4; ++r) l_i[r] = l_i[r] * alpha[r] + rsum[r];
#pragma unroll
        for (int nc = 0; nc < 8; ++nc)
#pragma unroll
            for (int r = 0; r < 4; ++r) oacc[nc][r] *= alpha[r];
        __syncthreads();

#pragma unroll
        for (int s2 = 0; s2 < 2; ++s2) {
            bf16x8 pa = *(const bf16x8*)&Ps[w][lr][s2 * 32 + lq * 8];
#pragma unroll
            for (int nc = 0; nc < 8; ++nc) {
                bf16x8 vf = *(const bf16x8*)&Vts[nc * 16 + lr][s2 * 32 + lq * 8];
                oacc[nc] =
                    __builtin_amdgcn_mfma_f32_16x16x32_bf16(pa, vf, oacc[nc], 0, 0, 0);
            }
        }
        __syncthreads();
    }

#pragma unroll
    for (int nc = 0; nc < 8; ++nc)
#pragma unroll
        for (int r = 0; r < 4; ++r) {
            int row = q0 + w * 16 + lq * 4 + r;
            O[(size_t)(b * T + row) * C + h * HD + nc * 16 + lr] =
                tobf(oacc[nc][r] / l_i[r]);
        }
}

// ---------------------------------------------------------------------------
extern "C" void kernel_launch(void* const* d_in, const int* in_sizes, int n_in,
                              void* d_out, int out_size, void* d_ws, size_t ws_size,
                              hipStream_t stream) {
    const void* x   = d_in[0];
    const void* wq  = d_in[1];
    const void* wk  = d_in[2];
    const void* wv  = d_in[3];
    const void* wo  = d_in[4];
    const void* fc1 = d_in[5];
    const void* fc2 = d_in[6];
    constexpr int Bv = 2, Tv = 2048, Cv = 2048, Hv = 16, MLP = 8192;
    constexpr int M = Bv * Tv;                  // 4096 rows
    constexpr size_t NE = (size_t)M * Cv;       // 8,388,608

    char* ws = (char*)d_ws;
    int*    flag = (int*)ws;                    // 256 B reserved
    __bf16* h  = (__bf16*)(ws + 256);
    __bf16* qb = h  + NE;
    __bf16* kb = qb + NE;
    __bf16* vt = kb + NE;                       // V, pre-transposed
    __bf16* ao = vt + NE;
    float*  x1 = (float*)(ao + NE);
    __bf16* mm = (__bf16*)(x1 + NE);            // [4096, 8192]
    // split-K partials (2 x NE fp32 = 67.1 MB) alias [h..vt] — both dead
    // when wo/fc2 run (QKV consumed h; attention consumed qb/kb/vt).
    float* part = (float*)h;

    detect_dtype_kernel<<<1, 64, 0, stream>>>((const unsigned short*)x, flag);

    rmsnorm_kernel<0><<<M, 256, 0, stream>>>(x, h, flag);

    gemm_qkv<<<dim3(48, 32), 256, 0, stream>>>(h, wq, wk, wv, qb, kb, vt, flag);

    attn_kernel<<<dim3(Tv / 64, Hv, Bv), 256, 0, stream>>>(qb, kb, vt, ao);

    // wo: split-K=2 -> partials, then reduce with residual x -> x1 (fp32)
    gemm_nt<4><<<dim3(16, 32, 2), 256, 0, stream>>>(ao, wo, part, M, Cv, Cv, flag);
    reduce_kernel<0><<<8192, 256, 0, stream>>>(part, part + NE, x, x1, flag);

    rmsnorm_kernel<1><<<M, 256, 0, stream>>>(x1, h, flag);

    gemm_nt<2><<<dim3(64, 32), 256, 0, stream>>>(h, fc1, mm, M, MLP, Cv, flag);

    // fc2: split-K=2 -> partials, then reduce with residual x1 -> d_out
    gemm_nt<4><<<dim3(16, 32, 2), 256, 0, stream>>>(mm, fc2, part, M, Cv, MLP, flag);
    reduce_kernel<1><<<8192, 256, 0, stream>>>(part, part + NE, x1, d_out, flag);
}

// Round 4
// 962.604 us; speedup vs baseline: 1.7108x; 1.1984x over previous
//
#include <hip/hip_runtime.h>

// ---------------------------------------------------------------------------
// TransformerBlock: B=2 T=2048 C=2048 H=16 HD=128 MLP=8192, causal, relu^2 MLP
// Round 4: attention rework — balanced q-tile pairing (uniform 33 iters/block),
// pre-scaled Q (exp2 softmax), diagonal-only masking, l via ones-column MFMA.
//
// mfma_f32_16x16x32_bf16 layouts (learn_hip m89/m91):
//   A[m=lane&15][k=(lane>>4)*8+j], B[n=lane&15][k=(lane>>4)*8+j]
//   D[row=(lane>>4)*4+reg][col=lane&15]
// ---------------------------------------------------------------------------

typedef __bf16 bf16x8 __attribute__((ext_vector_type(8)));
typedef __bf16 bf16x4 __attribute__((ext_vector_type(4)));
typedef float  f32x4  __attribute__((ext_vector_type(4)));

static __device__ __forceinline__ __bf16 tobf(float f) { return (__bf16)f; }

// async 16B global->LDS; lptr wave-uniform, HW writes lane l at lptr + l*16.
static __device__ __forceinline__ void async_copy16(const void* g, void* l) {
    __builtin_amdgcn_global_load_lds(
        (const __attribute__((address_space(1))) void*)g,
        (__attribute__((address_space(3))) void*)l, 16, 0, 0);
}

// ---------------------------------------------------------------------------
__global__ void detect_dtype_kernel(const unsigned short* __restrict__ xh,
                                    int* __restrict__ flag) {
    int t = threadIdx.x;                       // one wave of 64
    unsigned short u = xh[2 * t];              // even ushort slots
    int e = (u >> 7) & 0xFF;                   // bf16 exponent field
    bool outlier = (e < 100) || (e > 131);     // implausible for N(0,1)
    unsigned long long m = __ballot(outlier);
    if (t == 0) *flag = (__popcll(m) >= 16) ? 1 : 0;   // 1 => fp32 buffers
}

// ---------------------------------------------------------------------------
// rmsnorm: row of C=2048, one block per row, 256 threads x 8 elements.
template <int SRC>
__global__ __launch_bounds__(256) void rmsnorm_kernel(
    const void* __restrict__ xp, __bf16* __restrict__ h,
    const int* __restrict__ flagp) {
    constexpr int C = 2048;
    const int row = blockIdx.x, t = threadIdx.x;
    float vals[8];
    bool f32in = (SRC == 1) || (*flagp != 0);
    if (f32in) {
        const float4* xr = (const float4*)((const float*)xp + (size_t)row * C);
        float4 a = xr[2 * t], b = xr[2 * t + 1];
        vals[0] = a.x; vals[1] = a.y; vals[2] = a.z; vals[3] = a.w;
        vals[4] = b.x; vals[5] = b.y; vals[6] = b.z; vals[7] = b.w;
    } else {
        bf16x8 a = *((const bf16x8*)((const __bf16*)xp + (size_t)row * C) + t);
#pragma unroll
        for (int j = 0; j < 8; ++j) vals[j] = (float)a[j];
    }
    float ss = 0.f;
#pragma unroll
    for (int j = 0; j < 8; ++j) ss += vals[j] * vals[j];
#pragma unroll
    for (int off = 32; off > 0; off >>= 1) ss += __shfl_down(ss, off);
    __shared__ float red[4];
    if ((t & 63) == 0) red[t >> 6] = ss;
    __syncthreads();
    float mean = (red[0] + red[1] + red[2] + red[3]) * (1.0f / C);
    float sc = rsqrtf(mean + 1e-5f);
    bf16x8 o;
#pragma unroll
    for (int j = 0; j < 8; ++j) o[j] = tobf(vals[j] * sc);
    *((bf16x8*)(h + (size_t)row * C) + t) = o;
}

// ---------------------------------------------------------------------------
// NT GEMM: out = A[M,K](bf16) @ W[N,K]^T. 128x128 tile, BK=32, 4 waves.
// gridDim.z = split-K count. EPI 2: bf16 relu(acc)^2 (fc1);
// EPI 4: fp32 partial at outp + blockIdx.z*M*N (split-K).
template <int EPI>
__global__ __launch_bounds__(256) void gemm_nt(
    const __bf16* __restrict__ A, const void* __restrict__ Wp,
    void* __restrict__ outp, int M, int N, int K,
    const int* __restrict__ flagp) {
    __shared__ __align__(16) __bf16 As[128][32];
    __shared__ __align__(16) __bf16 Bs[128][32];
    const bool wf32 = (*flagp != 0);
    const int t = threadIdx.x;
    const int wave = t >> 6, lane = t & 63;
    const int lr = lane & 15, lq = lane >> 4;
    const int wm = wave & 1, wn = wave >> 1;
    const int m0 = blockIdx.y * 128, n0 = blockIdx.x * 128;
    const int kz = K / gridDim.z;
    const int kbeg = blockIdx.z * kz, kend = kbeg + kz;

    const int r0 = t >> 2, col0 = (t & 3) * 8;
    const int r1 = (t + 256) >> 2;
    const __bf16* gA0 = A + (size_t)(m0 + r0) * K + col0;
    const __bf16* gA1 = A + (size_t)(m0 + r1) * K + col0;
    const __bf16* gB0 = (const __bf16*)Wp + (size_t)(n0 + r0) * K + col0;
    const __bf16* gB1 = (const __bf16*)Wp + (size_t)(n0 + r1) * K + col0;
    __bf16* lA0 = &As[0][0] + (size_t)(wave * 64) * 8;
    __bf16* lA1 = &As[0][0] + (size_t)(256 + wave * 64) * 8;
    __bf16* lB0 = &Bs[0][0] + (size_t)(wave * 64) * 8;
    __bf16* lB1 = &Bs[0][0] + (size_t)(256 + wave * 64) * 8;

    f32x4 acc[4][4];
    const f32x4 zero = {0.f, 0.f, 0.f, 0.f};
#pragma unroll
    for (int i = 0; i < 4; ++i)
#pragma unroll
        for (int j = 0; j < 4; ++j) acc[i][j] = zero;

    for (int k0 = kbeg; k0 < kend; k0 += 32) {
        async_copy16(gA0 + k0, lA0);
        async_copy16(gA1 + k0, lA1);
        if (!wf32) {
            async_copy16(gB0 + k0, lB0);
            async_copy16(gB1 + k0, lB1);
        } else {
            const float* W = (const float*)Wp;
#pragma unroll
            for (int i = 0; i < 2; ++i) {
                int c = t + 256 * i;
                int r = c >> 2, col = (c & 3) * 8;
                float4 wa = *(const float4*)(W + (size_t)(n0 + r) * K + k0 + col);
                float4 wb = *(const float4*)(W + (size_t)(n0 + r) * K + k0 + col + 4);
                bf16x8 p = {tobf(wa.x), tobf(wa.y), tobf(wa.z), tobf(wa.w),
                            tobf(wb.x), tobf(wb.y), tobf(wb.z), tobf(wb.w)};
                *(bf16x8*)&Bs[r][col] = p;
            }
        }
        __syncthreads();
        bf16x8 a[4], b[4];
#pragma unroll
        for (int i = 0; i < 4; ++i)
            a[i] = *(const bf16x8*)&As[wm * 64 + i * 16 + lr][lq * 8];
#pragma unroll
        for (int j = 0; j < 4; ++j)
            b[j] = *(const bf16x8*)&Bs[wn * 64 + j * 16 + lr][lq * 8];
#pragma unroll
        for (int i = 0; i < 4; ++i)
#pragma unroll
            for (int j = 0; j < 4; ++j)
                acc[i][j] = __builtin_amdgcn_mfma_f32_16x16x32_bf16(
                    a[i], b[j], acc[i][j], 0, 0, 0);
        __syncthreads();
    }

    const size_t pbase = (size_t)blockIdx.z * ((size_t)M * N);
#pragma unroll
    for (int i = 0; i < 4; ++i)
#pragma unroll
        for (int j = 0; j < 4; ++j)
#pragma unroll
            for (int r = 0; r < 4; ++r) {
                int row = m0 + wm * 64 + i * 16 + lq * 4 + r;
                int col = n0 + wn * 64 + j * 16 + lr;
                size_t off = (size_t)row * N + col;
                float v = acc[i][j][r];
                if (EPI == 2) {
                    float rv = v > 0.f ? v : 0.f;
                    ((__bf16*)outp)[off] = tobf(rv * rv);
                } else {
                    ((float*)outp)[pbase + off] = v;
                }
            }
}

// ---------------------------------------------------------------------------
// Fused QKV GEMM: grid (48, 32). which = bx>>4 selects weight/output.
// Q output is PRE-SCALED by log2(e)/sqrt(HD) so attention softmax is exp2.
// V output is stored TRANSPOSED: Vt[(b*2048 + h*128+d)*2048 + t].
__global__ __launch_bounds__(256) void gemm_qkv(
    const __bf16* __restrict__ A, const void* __restrict__ wqp,
    const void* __restrict__ wkp, const void* __restrict__ wvp,
    __bf16* __restrict__ qout, __bf16* __restrict__ kout,
    __bf16* __restrict__ vtout, const int* __restrict__ flagp) {
    constexpr int N = 2048, K = 2048;
    constexpr float kQScale = 1.4426950408889634f * 0.08838834764831845f;
    __shared__ __align__(16) __bf16 As[128][32];
    __shared__ __align__(16) __bf16 Bs[128][32];
    const bool wf32 = (*flagp != 0);
    const int t = threadIdx.x;
    const int wave = t >> 6, lane = t & 63;
    const int lr = lane & 15, lq = lane >> 4;
    const int wm = wave & 1, wn = wave >> 1;
    const int which = blockIdx.x >> 4;
    const int m0 = blockIdx.y * 128, n0 = (blockIdx.x & 15) * 128;
    const void* Wp = (which == 0) ? wqp : (which == 1) ? wkp : wvp;

    const int r0 = t >> 2, col0 = (t & 3) * 8;
    const int r1 = (t + 256) >> 2;
    const __bf16* gA0 = A + (size_t)(m0 + r0) * K + col0;
    const __bf16* gA1 = A + (size_t)(m0 + r1) * K + col0;
    const __bf16* gB0 = (const __bf16*)Wp + (size_t)(n0 + r0) * K + col0;
    const __bf16* gB1 = (const __bf16*)Wp + (size_t)(n0 + r1) * K + col0;
    __bf16* lA0 = &As[0][0] + (size_t)(wave * 64) * 8;
    __bf16* lA1 = &As[0][0] + (size_t)(256 + wave * 64) * 8;
    __bf16* lB0 = &Bs[0][0] + (size_t)(wave * 64) * 8;
    __bf16* lB1 = &Bs[0][0] + (size_t)(256 + wave * 64) * 8;

    f32x4 acc[4][4];
    const f32x4 zero = {0.f, 0.f, 0.f, 0.f};
#pragma unroll
    for (int i = 0; i < 4; ++i)
#pragma unroll
        for (int j = 0; j < 4; ++j) acc[i][j] = zero;

    for (int k0 = 0; k0 < K; k0 += 32) {
        async_copy16(gA0 + k0, lA0);
        async_copy16(gA1 + k0, lA1);
        if (!wf32) {
            async_copy16(gB0 + k0, lB0);
            async_copy16(gB1 + k0, lB1);
        } else {
            const float* W = (const float*)Wp;
#pragma unroll
            for (int i = 0; i < 2; ++i) {
                int c = t + 256 * i;
                int r = c >> 2, col = (c & 3) * 8;
                float4 wa = *(const float4*)(W + (size_t)(n0 + r) * K + k0 + col);
                float4 wb = *(const float4*)(W + (size_t)(n0 + r) * K + k0 + col + 4);
                bf16x8 p = {tobf(wa.x), tobf(wa.y), tobf(wa.z), tobf(wa.w),
                            tobf(wb.x), tobf(wb.y), tobf(wb.z), tobf(wb.w)};
                *(bf16x8*)&Bs[r][col] = p;
            }
        }
        __syncthreads();
        bf16x8 a[4], b[4];
#pragma unroll
        for (int i = 0; i < 4; ++i)
            a[i] = *(const bf16x8*)&As[wm * 64 + i * 16 + lr][lq * 8];
#pragma unroll
        for (int j = 0; j < 4; ++j)
            b[j] = *(const bf16x8*)&Bs[wn * 64 + j * 16 + lr][lq * 8];
#pragma unroll
        for (int i = 0; i < 4; ++i)
#pragma unroll
            for (int j = 0; j < 4; ++j)
                acc[i][j] = __builtin_amdgcn_mfma_f32_16x16x32_bf16(
                    a[i], b[j], acc[i][j], 0, 0, 0);
        __syncthreads();
    }

    if (which < 2) {
        __bf16* outp = (which == 0) ? qout : kout;
        const float sc = (which == 0) ? kQScale : 1.0f;
#pragma unroll
        for (int i = 0; i < 4; ++i)
#pragma unroll
            for (int j = 0; j < 4; ++j)
#pragma unroll
                for (int r = 0; r < 4; ++r) {
                    int row = m0 + wm * 64 + i * 16 + lq * 4 + r;
                    int col = n0 + wn * 64 + j * 16 + lr;
                    outp[(size_t)row * N + col] = tobf(acc[i][j][r] * sc);
                }
    } else {
#pragma unroll
        for (int i = 0; i < 4; ++i)
#pragma unroll
            for (int j = 0; j < 4; ++j) {
                int t0 = m0 + wm * 64 + i * 16 + lq * 4;   // token index (4 consec)
                int b  = t0 >> 11, tt = t0 & 2047;
                int col = n0 + wn * 64 + j * 16 + lr;      // h*128 + d
                bf16x4 p = {tobf(acc[i][j][0]), tobf(acc[i][j][1]),
                            tobf(acc[i][j][2]), tobf(acc[i][j][3])};
                *(bf16x4*)(vtout + (((size_t)(b * 2048 + col)) << 11) + tt) = p;
            }
    }
}

// ---------------------------------------------------------------------------
// Split-K reduce + residual.
// MODE 0: out fp32 = res(dtype per flag) + p0 + p1          (wo -> x1)
// MODE 1: out(dtype per flag) = res(fp32) + p0 + p1         (fc2 -> d_out)
template <int MODE>
__global__ __launch_bounds__(256) void reduce_kernel(
    const float* __restrict__ p0, const float* __restrict__ p1,
    const void* __restrict__ resp, void* __restrict__ outp,
    const int* __restrict__ flagp) {
    const bool f32 = (*flagp != 0);
    size_t i = ((size_t)blockIdx.x * 256 + threadIdx.x) * 4;
    float4 a = *(const float4*)(p0 + i);
    float4 b = *(const float4*)(p1 + i);
    float rx, ry, rz, rw;
    if (MODE == 1 || f32) {
        float4 r = *(const float4*)((const float*)resp + i);
        rx = r.x; ry = r.y; rz = r.z; rw = r.w;
    } else {
        bf16x4 rb = *(const bf16x4*)((const __bf16*)resp + i);
        rx = (float)rb[0]; ry = (float)rb[1]; rz = (float)rb[2]; rw = (float)rb[3];
    }
    float ox = rx + a.x + b.x, oy = ry + a.y + b.y;
    float oz = rz + a.z + b.z, ow = rw + a.w + b.w;
    if (MODE == 0 || f32) {
        float4 o = {ox, oy, oz, ow};
        *(float4*)((float*)outp + i) = o;
    } else {
        bf16x4 o = {tobf(ox), tobf(oy), tobf(oz), tobf(ow)};
        *(bf16x4*)((__bf16*)outp + i) = o;
    }
}

// ---------------------------------------------------------------------------
// Causal flash attention, load-balanced. Grid (16, H, B), block 256 (4 waves).
// Each block runs TWO q-tiles: blockIdx.x and 31-blockIdx.x -> uniform 33
// k-iterations per block. Q is pre-scaled (log2 domain, exp2 softmax).
// V pre-transposed: Vt[(b*2048 + h*128 + d)*2048 + t].
// Row-sums l accumulate via a ones-column MFMA alongside O (same rescaling).
__global__ __launch_bounds__(256) void attn_kernel(
    const __bf16* __restrict__ Q, const __bf16* __restrict__ K,
    const __bf16* __restrict__ Vt, __bf16* __restrict__ O) {
    constexpr int T = 2048, C = 2048, HD = 128;
    __shared__ __align__(16) __bf16 Ks[64][136];
    __shared__ __align__(16) __bf16 Vts[128][72];
    __shared__ __align__(16) __bf16 Ps[4][16][72];
    const int t = threadIdx.x, w = t >> 6, lane = t & 63;
    const int lr = lane & 15, lq = lane >> 4;
    const int b = blockIdx.z, h = blockIdx.y;
    const __bf16* vtb = Vt + ((size_t)(b * 2048 + h * 128) << 11);
    const f32x4 zero = {0.f, 0.f, 0.f, 0.f};

    // ones B-fragment: B[n][k] = (n==0), for the l-accumulator column
    bf16x8 ones;
#pragma unroll
    for (int j = 0; j < 8; ++j) ones[j] = (lr == 0) ? (__bf16)1.0f : (__bf16)0.0f;

    for (int pass = 0; pass < 2; ++pass) {
        const int qblk = (pass == 0) ? blockIdx.x : 31 - blockIdx.x;
        const int q0 = qblk * 64;

        const int qrow = q0 + w * 16 + lr;
        const __bf16* qb = Q + (size_t)(b * T + qrow) * C + h * HD;
        bf16x8 qf[4];
#pragma unroll
        for (int s = 0; s < 4; ++s)
            qf[s] = *(const bf16x8*)(qb + s * 32 + lq * 8);

        f32x4 oacc[8], lacc = zero;
#pragma unroll
        for (int nc = 0; nc < 8; ++nc) oacc[nc] = zero;
        float m_i[4] = {-3e38f, -3e38f, -3e38f, -3e38f};

        for (int kb = 0; kb <= qblk; ++kb) {
            const int k00 = kb * 64;
#pragma unroll
            for (int i = 0; i < 4; ++i) {
                int c = t + 256 * i;
                int r = c >> 4, col = (c & 15) * 8;
                *(bf16x8*)&Ks[r][col] =
                    *(const bf16x8*)(K + (size_t)(b * T + k00 + r) * C + h * HD + col);
            }
#pragma unroll
            for (int i = 0; i < 4; ++i) {
                int c = t + 256 * i;
                int r = c >> 3, cg = (c & 7) * 8;
                *(bf16x8*)&Vts[r][cg] =
                    *(const bf16x8*)(vtb + ((size_t)r << 11) + k00 + cg);
            }
            __syncthreads();

            float pv[4][4];
#pragma unroll
            for (int jc = 0; jc < 4; ++jc) {
                f32x4 s = zero;
#pragma unroll
                for (int ks = 0; ks < 4; ++ks) {
                    bf16x8 kf = *(const bf16x8*)&Ks[jc * 16 + lr][ks * 32 + lq * 8];
                    s = __builtin_amdgcn_mfma_f32_16x16x32_bf16(qf[ks], kf, s, 0, 0, 0);
                }
#pragma unroll
                for (int r = 0; r < 4; ++r) pv[jc][r] = s[r];
            }
            if (kb == qblk) {   // diagonal block: causal mask (wave-uniform branch)
#pragma unroll
                for (int jc = 0; jc < 4; ++jc)
#pragma unroll
                    for (int r = 0; r < 4; ++r)
                        if (jc * 16 + lr > w * 16 + lq * 4 + r) pv[jc][r] = -3e38f;
            }
            float rmax[4];
#pragma unroll
            for (int r = 0; r < 4; ++r)
                rmax[r] = fmaxf(fmaxf(pv[0][r], pv[1][r]), fmaxf(pv[2][r], pv[3][r]));
#pragma unroll
            for (int off = 1; off < 16; off <<= 1)
#pragma unroll
                for (int r = 0; r < 4; ++r)
                    rmax[r] = fmaxf(rmax[r], __shfl_xor(rmax[r], off));
            float alpha[4];
#pragma unroll
            for (int r = 0; r < 4; ++r) {
                float mn = fmaxf(m_i[r], rmax[r]);
                alpha[r] = exp2f(m_i[r] - mn);
                m_i[r] = mn;
            }
#pragma unroll
            for (int jc = 0; jc < 4; ++jc)
#pragma unroll
                for (int r = 0; r < 4; ++r)
                    Ps[w][lq * 4 + r][jc * 16 + lr] = tobf(exp2f(pv[jc][r] - m_i[r]));
#pragma unroll
            for (int nc = 0; nc < 8; ++nc)
#pragma unroll
                for (int r = 0; r < 4; ++r) oacc[nc][r] *= alpha[r];
#pragma unroll
            for (int r = 0; r < 4; ++r) lacc[r] *= alpha[r];
            __syncthreads();   // P visible before PV reads

#pragma unroll
            for (int s2 = 0; s2 < 2; ++s2) {
                bf16x8 pa = *(const bf16x8*)&Ps[w][lr][s2 * 32 + lq * 8];
#pragma unroll
                for (int nc = 0; nc < 8; ++nc) {
                    bf16x8 vf = *(const bf16x8*)&Vts[nc * 16 + lr][s2 * 32 + lq * 8];
                    oacc[nc] = __builtin_amdgcn_mfma_f32_16x16x32_bf16(
                        pa, vf, oacc[nc], 0, 0, 0);
                }
                lacc = __builtin_amdgcn_mfma_f32_16x16x32_bf16(pa, ones, lacc, 0, 0, 0);
            }
            __syncthreads();   // PV reads done before next staging overwrite
        }

        // l lives in lanes lr==0 (col 0); broadcast within the 16-lane row group
        float inv[4];
#pragma unroll
        for (int r = 0; r < 4; ++r) inv[r] = 1.0f / __shfl(lacc[r], lane & 48);
#pragma unroll
        for (int nc = 0; nc < 8; ++nc)
#pragma unroll
            for (int r = 0; r < 4; ++r) {
                int row = q0 + w * 16 + lq * 4 + r;
                O[(size_t)(b * T + row) * C + h * HD + nc * 16 + lr] =
                    tobf(oacc[nc][r] * inv[r]);
            }
        __syncthreads();       // pass-1 staging must not race pass-0 epilogue
    }
}

// ---------------------------------------------------------------------------
extern "C" void kernel_launch(void* const* d_in, const int* in_sizes, int n_in,
                              void* d_out, int out_size, void* d_ws, size_t ws_size,
                              hipStream_t stream) {
    const void* x   = d_in[0];
    const void* wq  = d_in[1];
    const void* wk  = d_in[2];
    const void* wv  = d_in[3];
    const void* wo  = d_in[4];
    const void* fc1 = d_in[5];
    const void* fc2 = d_in[6];
    constexpr int Bv = 2, Tv = 2048, Cv = 2048, Hv = 16, MLP = 8192;
    constexpr int M = Bv * Tv;                  // 4096 rows
    constexpr size_t NE = (size_t)M * Cv;       // 8,388,608

    char* ws = (char*)d_ws;
    int*    flag = (int*)ws;                    // 256 B reserved
    __bf16* h  = (__bf16*)(ws + 256);
    __bf16* qb = h  + NE;
    __bf16* kb = qb + NE;
    __bf16* vt = kb + NE;                       // V, pre-transposed
    __bf16* ao = vt + NE;
    float*  x1 = (float*)(ao + NE);
    __bf16* mm = (__bf16*)(x1 + NE);            // [4096, 8192]
    float* part = (float*)h;                    // split-K partials alias h..vt

    detect_dtype_kernel<<<1, 64, 0, stream>>>((const unsigned short*)x, flag);

    rmsnorm_kernel<0><<<M, 256, 0, stream>>>(x, h, flag);

    gemm_qkv<<<dim3(48, 32), 256, 0, stream>>>(h, wq, wk, wv, qb, kb, vt, flag);

    attn_kernel<<<dim3(16, Hv, Bv), 256, 0, stream>>>(qb, kb, vt, ao);

    // wo: split-K=2 -> partials, then reduce with residual x -> x1 (fp32)
    gemm_nt<4><<<dim3(16, 32, 2), 256, 0, stream>>>(ao, wo, part, M, Cv, Cv, flag);
    reduce_kernel<0><<<8192, 256, 0, stream>>>(part, part + NE, x, x1, flag);

    rmsnorm_kernel<1><<<M, 256, 0, stream>>>(x1, h, flag);

    gemm_nt<2><<<dim3(64, 32), 256, 0, stream>>>(h, fc1, mm, M, MLP, Cv, flag);

    // fc2: split-K=2 -> partials, then reduce with residual x1 -> d_out
    gemm_nt<4><<<dim3(16, 32, 2), 256, 0, stream>>>(mm, fc2, part, M, Cv, MLP, flag);
    reduce_kernel<1><<<8192, 256, 0, stream>>>(part, part + NE, x1, d_out, flag);
}